// Round 15
// baseline (193.092 us; speedup 1.0000x reference)
//
#include <hip/hip_runtime.h>
#include <math.h>

#define NB     262144   // batch (tokens)
#define DD     512      // d_routing
#define NG     4        // groups
#define NGS    4        // group size
#define NOUT   20       // 4 group logits + 16 in-group logits

#define TPB    256      // 4 waves
#define TOKS   256      // tokens per block
#define TCH    16       // tokens per chunk (16 full rows = 32KB contiguous)
#define NCHUNK (TOKS / TCH)   // 16

typedef float f32x4 __attribute__((ext_vector_type(4)));

// Proven-safe staging shape only: single buffer, stage -> full drain
// (__syncthreads) -> compute. LDS dest wave-uniform + compile-time.
#define GLOAD_LDS16(gsrc, ldst)                                                \
    __builtin_amdgcn_global_load_lds(                                          \
        (const __attribute__((address_space(1))) unsigned int*)(gsrc),         \
        (__attribute__((address_space(3))) unsigned int*)(ldst), 16, 0, 0)

// Contiguous-stream staging: chunk = 16 whole token rows. Each instruction
// reads 64 lanes x 16B = 1KB FULLY CONTIGUOUS (the fillBuffer pattern that
// sustains 6.7 TB/s), vs the 2KB-strided 128B segments of R1..R14 that were
// stuck at ~3.1 TB/s (HBM page-thrash: one activate per 128B).
__global__ __launch_bounds__(TPB, 2) void router_k(
    const float* __restrict__ x,        // [NB, DD]
    const float* __restrict__ group_w,  // [NG, DD]
    const float* __restrict__ group_b,  // [NG]
    const float* __restrict__ in_w,     // [NG*NGS, DD]
    const float* __restrict__ in_b,     // [NG, NGS]
    const int*   __restrict__ experts,  // [NG, NGS]
    float*       __restrict__ out)      // [2*NB*2]: indices then weights, fp32
{
    __shared__ float xlds[TCH * DD];    // 32768 B: 16 token rows
    __shared__ float wlds[NOUT * DD];   // 40960 B: rows 0..3 group_w, 4..19 in_w

    const int tid  = threadIdx.x;
    const int wid  = tid >> 6;          // 0..3
    const int lane = tid & 63;
    const int tok0 = blockIdx.x * TOKS;

    // ---- stage w once (proven prologue, vector loads) ----
    {
        const float4* gw4 = reinterpret_cast<const float4*>(group_w);
        const float4* iw4 = reinterpret_cast<const float4*>(in_w);
        float4* wl4 = reinterpret_cast<float4*>(wlds);
        for (int i = tid; i < (NG * DD) / 4; i += TPB)
            wl4[i] = gw4[i];
        for (int i = tid; i < (NG * NGS * DD) / 4; i += TPB)
            wl4[(NG * DD) / 4 + i] = iw4[i];
    }
    __syncthreads();

    // Cooperative compute mapping: 16 threads per token.
    const int tt = tid >> 4;            // token-in-chunk (0..15)
    const int sl = tid & 15;            // slice owner (0..15)

    float2* outi = reinterpret_cast<float2*>(out);
    float2* outw = reinterpret_cast<float2*>(out + (size_t)NB * 2);

#pragma unroll 1
    for (int ch = 0; ch < NCHUNK; ++ch) {
        // ---- stage: wave wid covers tokens wid*4..wid*4+3 (8KB sequential).
        // Instr i: token wid*4+(i>>1), half-row (i&1): 1KB contiguous.
#pragma unroll
        for (int i = 0; i < 8; ++i) {
            const int tl   = wid * 4 + (i >> 1);
            const int half = i & 1;
            const float* src =
                x + (size_t)(tok0 + ch * TCH + tl) * DD + half * 256 + lane * 4;
            GLOAD_LDS16(src, &xlds[tl * DD + half * 256]);
        }
        __syncthreads();   // vmcnt(0) drain + barrier: chunk rows ready

        // ---- compute: thread (tt, sl) covers token tt, dims j*64 + sl*4.
        float acc[NOUT];
#pragma unroll
        for (int o = 0; o < NOUT; ++o) acc[o] = 0.f;

#pragma unroll
        for (int j = 0; j < 8; ++j) {
            const f32x4 xv =
                *(const f32x4*)&xlds[tt * DD + j * 64 + sl * 4];
#pragma unroll
            for (int o = 0; o < NOUT; ++o) {
                const f32x4 wv =
                    *(const f32x4*)&wlds[o * DD + j * 64 + sl * 4];
                float a = acc[o];
                a = fmaf(xv.x, wv.x, a);
                a = fmaf(xv.y, wv.y, a);
                a = fmaf(xv.z, wv.z, a);
                a = fmaf(xv.w, wv.w, a);
                acc[o] = a;
            }
        }

        // ---- reduce across the 16 slice-owners (tree; lanes end with sum).
#pragma unroll
        for (int o = 0; o < NOUT; ++o) {
            float v = acc[o];
            v += __shfl_xor(v, 1);
            v += __shfl_xor(v, 2);
            v += __shfl_xor(v, 4);
            v += __shfl_xor(v, 8);
            acc[o] = v;
        }

        // ---- epilogue (redundant in 16 lanes; sl==0 writes) ----
        float gl[NG];
#pragma unroll
        for (int g = 0; g < NG; ++g) gl[g] = acc[g] + group_b[g];
        int bg = 0;
        float bv = gl[0];
#pragma unroll
        for (int g = 1; g < NG; ++g)
            if (gl[g] > bv) { bv = gl[g]; bg = g; }

        float il[NGS];
#pragma unroll
        for (int k = 0; k < NGS; ++k) il[k] = 0.f;
#pragma unroll
        for (int g = 0; g < NG; ++g) {
            const bool sel = (g == bg);
#pragma unroll
            for (int k = 0; k < NGS; ++k)
                il[k] = sel ? acc[NG + g * NGS + k] : il[k];
        }
#pragma unroll
        for (int k = 0; k < NGS; ++k) il[k] += in_b[bg * NGS + k];

        float m = fmaxf(fmaxf(il[0], il[1]), fmaxf(il[2], il[3]));
        float p[NGS];
        float s = 0.f;
#pragma unroll
        for (int k = 0; k < NGS; ++k) { p[k] = expf(il[k] - m); s += p[k]; }
        const float inv = 1.0f / s;
#pragma unroll
        for (int k = 0; k < NGS; ++k) p[k] *= inv;

        int i1 = 0;
        float v1 = p[0];
#pragma unroll
        for (int k = 1; k < NGS; ++k)
            if (p[k] > v1) { v1 = p[k]; i1 = k; }
        int i2 = -1;
        float v2 = -3.0e38f;
#pragma unroll
        for (int k = 0; k < NGS; ++k)
            if (k != i1 && p[k] > v2) { v2 = p[k]; i2 = k; }

        if (sl == 0) {
            const int t = tok0 + ch * TCH + tt;
            const int id1 = experts[bg * NGS + i1];
            const int id2 = experts[bg * NGS + i2];
            outi[t] = make_float2((float)id1, (float)id2);
            outw[t] = make_float2(v1, v2);
        }

        __syncthreads();   // all compute reads done before next stage
    }
}

extern "C" void kernel_launch(void* const* d_in, const int* in_sizes, int n_in,
                              void* d_out, int out_size, void* d_ws, size_t ws_size,
                              hipStream_t stream) {
    const float* x  = (const float*)d_in[0];
    const float* gw = (const float*)d_in[1];
    const float* gb = (const float*)d_in[2];
    const float* iw = (const float*)d_in[3];
    const float* ib = (const float*)d_in[4];
    const int*   et = (const int*)d_in[5];
    float* out = (float*)d_out;

    router_k<<<dim3(NB / TOKS), dim3(TPB), 0, stream>>>(x, gw, gb, iw, ib, et, out);
}

// Round 16
// 166.455 us; speedup vs baseline: 1.1600x; 1.1600x over previous
//
#include <hip/hip_runtime.h>
#include <math.h>

#define NB     262144   // batch (tokens)
#define DD     512      // d_routing
#define NG     4        // groups
#define NGS    4        // group size
#define NOUT   20       // 4 group logits + 16 in-group logits

#define TPB    256      // 4 waves/block; 2 blocks/CU (LDS) -> 8 free-running waves
#define NCHUNK 16       // D chunks
#define CH     32       // floats per token per chunk (one full 128B line)
#define TSLOT  36       // padded floats per token slot (144B: quad stride 9 -> conflict-free)

typedef float f32x4 __attribute__((ext_vector_type(4)));

// Wave-private staging, ZERO main-loop barriers:
//   per chunk, each wave: 8x global_load_dwordx4 (8 full 128B lines each,
//   perfectly coalesced) -> VGPR -> ds_write_b128 into the wave's PRIVATE
//   LDS region -> per-thread ds_read_b128 + FMA.
// Cross-lane sharing happens only within the wave, so the compiler's own
// lgkmcnt/vmcnt waits are sufficient -- no __syncthreads, no phase-locking
// of blocks (the R5/R11/R14 limiter: stage/compute serialized per block and
// blocks locked in phase -> HBM duty ~53%). 8 waves/CU free-run; memory
// stays busy continuously. No global_load_lds (R6-R13 pathologies avoided).
__global__ __launch_bounds__(TPB, 2) void router_k(
    const float* __restrict__ x,        // [NB, DD]
    const float* __restrict__ group_w,  // [NG, DD]
    const float* __restrict__ group_b,  // [NG]
    const float* __restrict__ in_w,     // [NG*NGS, DD]
    const float* __restrict__ in_b,     // [NG, NGS]
    const int*   __restrict__ experts,  // [NG, NGS]
    float*       __restrict__ out)      // [2*NB*2]: indices then weights, fp32
{
    __shared__ float wlds[NOUT * DD];        // 40960B: rows 0..3 gw, 4..19 in_w
    __shared__ float xw[4 * 64 * TSLOT];     // 36864B: 4 wave-private regions

    const int tid  = threadIdx.x;
    const int wid  = tid >> 6;               // 0..3
    const int lane = tid & 63;
    const int tok0 = blockIdx.x * TPB;

    // ---- stage w once (proven prologue; only barrier in the kernel) ----
    {
        const float4* gw4 = reinterpret_cast<const float4*>(group_w);
        const float4* iw4 = reinterpret_cast<const float4*>(in_w);
        float4* wl4 = reinterpret_cast<float4*>(wlds);
        for (int i = tid; i < (NG * DD) / 4; i += TPB)
            wl4[i] = gw4[i];
        for (int i = tid; i < (NG * NGS * DD) / 4; i += TPB)
            wl4[(NG * DD) / 4 + i] = iw4[i];
    }
    __syncthreads();

    // ---- wave-private pointers ----
    float* xreg = &xw[wid * 64 * TSLOT];
    // Staging: instr m covers wave-token (8m + lane>>3), quad c = lane&7.
    const float* xsrc =
        x + (size_t)(tok0 + wid * 64 + (lane >> 3)) * DD + (lane & 7) * 4;
    float* xwr = &xreg[(lane >> 3) * TSLOT + (lane & 7) * 4];
    // Compute: this thread's own token slot.
    const float* xt = &xreg[lane * TSLOT];

    float acc[NOUT];
#pragma unroll
    for (int o = 0; o < NOUT; ++o) acc[o] = 0.f;

#pragma unroll 1
    for (int ch = 0; ch < NCHUNK; ++ch) {
        const int dd = ch * CH;

        // 8 coalesced line-loads -> named VGPRs (independent; issue together)
        f32x4 r0 = *(const f32x4*)(xsrc + 0 * 8 * DD + dd);
        f32x4 r1 = *(const f32x4*)(xsrc + 1 * 8 * DD + dd);
        f32x4 r2 = *(const f32x4*)(xsrc + 2 * 8 * DD + dd);
        f32x4 r3 = *(const f32x4*)(xsrc + 3 * 8 * DD + dd);
        f32x4 r4 = *(const f32x4*)(xsrc + 4 * 8 * DD + dd);
        f32x4 r5 = *(const f32x4*)(xsrc + 5 * 8 * DD + dd);
        f32x4 r6 = *(const f32x4*)(xsrc + 6 * 8 * DD + dd);
        f32x4 r7 = *(const f32x4*)(xsrc + 7 * 8 * DD + dd);

        // wave-private ds_writes (compiler inserts the vmcnt waits)
        *(f32x4*)(xwr + 0 * 8 * TSLOT) = r0;
        *(f32x4*)(xwr + 1 * 8 * TSLOT) = r1;
        *(f32x4*)(xwr + 2 * 8 * TSLOT) = r2;
        *(f32x4*)(xwr + 3 * 8 * TSLOT) = r3;
        *(f32x4*)(xwr + 4 * 8 * TSLOT) = r4;
        *(f32x4*)(xwr + 5 * 8 * TSLOT) = r5;
        *(f32x4*)(xwr + 6 * 8 * TSLOT) = r6;
        *(f32x4*)(xwr + 7 * 8 * TSLOT) = r7;

        // compute (compiler inserts lgkmcnt wait before the aliasing reads)
#pragma unroll
        for (int g = 0; g < 8; ++g) {
            const f32x4 xv = *(const f32x4*)(xt + g * 4);
#pragma unroll
            for (int o = 0; o < NOUT; ++o) {
                const f32x4 wv = *(const f32x4*)&wlds[o * DD + dd + g * 4];
                float a = acc[o];
                a = fmaf(xv.x, wv.x, a);
                a = fmaf(xv.y, wv.y, a);
                a = fmaf(xv.z, wv.z, a);
                a = fmaf(xv.w, wv.w, a);
                acc[o] = a;
            }
        }
    }

    // ---- epilogue (one token per thread; proven R11 path) ----
    const int t = tok0 + tid;

    float gl[NG];
#pragma unroll
    for (int g = 0; g < NG; ++g) gl[g] = acc[g] + group_b[g];
    int bg = 0;
    float bv = gl[0];
#pragma unroll
    for (int g = 1; g < NG; ++g)
        if (gl[g] > bv) { bv = gl[g]; bg = g; }

    float il[NGS];
#pragma unroll
    for (int k = 0; k < NGS; ++k) il[k] = 0.f;
#pragma unroll
    for (int g = 0; g < NG; ++g) {
        const bool sel = (g == bg);
#pragma unroll
        for (int k = 0; k < NGS; ++k)
            il[k] = sel ? acc[NG + g * NGS + k] : il[k];
    }
#pragma unroll
    for (int k = 0; k < NGS; ++k) il[k] += in_b[bg * NGS + k];

    float m = fmaxf(fmaxf(il[0], il[1]), fmaxf(il[2], il[3]));
    float p[NGS];
    float s = 0.f;
#pragma unroll
    for (int k = 0; k < NGS; ++k) { p[k] = expf(il[k] - m); s += p[k]; }
    const float inv = 1.0f / s;
#pragma unroll
    for (int k = 0; k < NGS; ++k) p[k] *= inv;

    int i1 = 0;
    float v1 = p[0];
#pragma unroll
    for (int k = 1; k < NGS; ++k)
        if (p[k] > v1) { v1 = p[k]; i1 = k; }
    int i2 = -1;
    float v2 = -3.0e38f;
#pragma unroll
    for (int k = 0; k < NGS; ++k)
        if (k != i1 && p[k] > v2) { v2 = p[k]; i2 = k; }

    const int id1 = experts[bg * NGS + i1];
    const int id2 = experts[bg * NGS + i2];

    float2* outi = reinterpret_cast<float2*>(out);
    float2* outw = reinterpret_cast<float2*>(out + (size_t)NB * 2);
    outi[t] = make_float2((float)id1, (float)id2);
    outw[t] = make_float2(v1, v2);
}

extern "C" void kernel_launch(void* const* d_in, const int* in_sizes, int n_in,
                              void* d_out, int out_size, void* d_ws, size_t ws_size,
                              hipStream_t stream) {
    const float* x  = (const float*)d_in[0];
    const float* gw = (const float*)d_in[1];
    const float* gb = (const float*)d_in[2];
    const float* iw = (const float*)d_in[3];
    const float* ib = (const float*)d_in[4];
    const int*   et = (const int*)d_in[5];
    float* out = (float*)d_out;

    router_k<<<dim3(NB / TPB), dim3(TPB), 0, stream>>>(x, gw, gb, iw, ib, et, out);
}

// Round 17
// 142.684 us; speedup vs baseline: 1.3533x; 1.1666x over previous
//
#include <hip/hip_runtime.h>
#include <math.h>

#define NB     262144   // batch (tokens)
#define DD     512      // d_routing
#define NG     4        // groups
#define NGS    4        // group size
#define NOUT   20       // 4 group logits + 16 in-group logits

#define TPB    256      // 4 waves/block; 40KB LDS -> 4 blocks/CU = 16 waves
#define TOKS   256      // tokens per block; wave owns 64 = 4 passes x 16

typedef float f32x4 __attribute__((ext_vector_type(4)));

// Cooperative-token, x-in-registers scheme. Lane = (tg = lane>>3, d8 = lane&7):
// 8 lanes per token; lane loads x[t, it*32 + d8*4 .. +4] straight to VGPR and
// consumes it immediately (FMA vs the same w-slice from LDS). Properties:
//  - every global_load_dwordx4 covers 8 FULL 128B lines, each consumed exactly
//    once by that instruction (no L1 reuse needed -> no thrash, unlike R1/R4);
//  - x never flows through LDS (no ds_write/ds_read chain like R16);
//  - no barriers in the main loop; 16 waves/CU free-run with ~16KB of reads
//    in flight per wave (Little's-law saturating);
//  - T=2 tokens per lane (t, t+8) share every w-read.
// Spill-proofing (R10/R13 lesson: compiler squeezed VGPR=64 and spilled):
// lb(256,2) caps occupancy pressure, unroll 4 keeps <=8 xv vectors live.
__global__ __launch_bounds__(TPB, 2) void router_k(
    const float* __restrict__ x,        // [NB, DD]
    const float* __restrict__ group_w,  // [NG, DD]
    const float* __restrict__ group_b,  // [NG]
    const float* __restrict__ in_w,     // [NG*NGS, DD]
    const float* __restrict__ in_b,     // [NG, NGS]
    const int*   __restrict__ experts,  // [NG, NGS]
    float*       __restrict__ out)      // [2*NB*2]: indices then weights, fp32
{
    __shared__ float wlds[NOUT * DD];   // 40960B: rows 0..3 gw, 4..19 in_w
    {
        const float4* gw4 = reinterpret_cast<const float4*>(group_w);
        const float4* iw4 = reinterpret_cast<const float4*>(in_w);
        float4* wl4 = reinterpret_cast<float4*>(wlds);
        for (int i = threadIdx.x; i < (NG * DD) / 4; i += TPB)
            wl4[i] = gw4[i];
        for (int i = threadIdx.x; i < (NG * NGS * DD) / 4; i += TPB)
            wl4[(NG * DD) / 4 + i] = iw4[i];
    }
    __syncthreads();   // only barrier in the kernel

    const int tid  = threadIdx.x;
    const int wid  = tid >> 6;
    const int lane = tid & 63;
    const int tg   = lane >> 3;         // token-in-pass (0..7)
    const int d8   = lane & 7;          // d-slice owner (0..7)
    const int wtok0 = blockIdx.x * TOKS + wid * 64;

    float2* outi = reinterpret_cast<float2*>(out);
    float2* outw = reinterpret_cast<float2*>(out + (size_t)NB * 2);

#pragma unroll 1
    for (int p = 0; p < 4; ++p) {
        const int t0 = wtok0 + p * 16 + tg;      // second token: t0 + 8
        const float* xr0 = x + (size_t)t0 * DD + d8 * 4;
        const float* xr1 = xr0 + 8 * DD;

        float acc0[NOUT], acc1[NOUT];
#pragma unroll
        for (int o = 0; o < NOUT; ++o) { acc0[o] = 0.f; acc1[o] = 0.f; }

#pragma unroll 4
        for (int it = 0; it < 16; ++it) {
            const f32x4 xv0 = *(const f32x4*)(xr0 + it * 32);
            const f32x4 xv1 = *(const f32x4*)(xr1 + it * 32);
#pragma unroll
            for (int o = 0; o < NOUT; ++o) {
                const f32x4 wv =
                    *(const f32x4*)&wlds[o * DD + it * 32 + d8 * 4];
                float a0 = acc0[o];
                float a1 = acc1[o];
                a0 = fmaf(xv0.x, wv.x, a0); a1 = fmaf(xv1.x, wv.x, a1);
                a0 = fmaf(xv0.y, wv.y, a0); a1 = fmaf(xv1.y, wv.y, a1);
                a0 = fmaf(xv0.z, wv.z, a0); a1 = fmaf(xv1.z, wv.z, a1);
                a0 = fmaf(xv0.w, wv.w, a0); a1 = fmaf(xv1.w, wv.w, a1);
                acc0[o] = a0;
                acc1[o] = a1;
            }
        }

        // Reduce partials across the 8-lane d-slice group (xor 1,2,4).
#pragma unroll
        for (int o = 0; o < NOUT; ++o) {
            float v0 = acc0[o];
            v0 += __shfl_xor(v0, 1);
            v0 += __shfl_xor(v0, 2);
            v0 += __shfl_xor(v0, 4);
            acc0[o] = v0;
            float v1 = acc1[o];
            v1 += __shfl_xor(v1, 1);
            v1 += __shfl_xor(v1, 2);
            v1 += __shfl_xor(v1, 4);
            acc1[o] = v1;
        }

        // ---- epilogue for both tokens (proven path; d8==0 writes) ----
#pragma unroll
        for (int tk = 0; tk < 2; ++tk) {
            const float* acc = (tk == 0) ? acc0 : acc1;  // unroll-const select
            const int t = t0 + tk * 8;

            float gl[NG];
#pragma unroll
            for (int g = 0; g < NG; ++g) gl[g] = acc[g] + group_b[g];
            int bg = 0;
            float bv = gl[0];
#pragma unroll
            for (int g = 1; g < NG; ++g)
                if (gl[g] > bv) { bv = gl[g]; bg = g; }

            float il[NGS];
#pragma unroll
            for (int k = 0; k < NGS; ++k) il[k] = 0.f;
#pragma unroll
            for (int g = 0; g < NG; ++g) {
                const bool sel = (g == bg);
#pragma unroll
                for (int k = 0; k < NGS; ++k)
                    il[k] = sel ? acc[NG + g * NGS + k] : il[k];
            }
#pragma unroll
            for (int k = 0; k < NGS; ++k) il[k] += in_b[bg * NGS + k];

            float m = fmaxf(fmaxf(il[0], il[1]), fmaxf(il[2], il[3]));
            float pr[NGS];
            float s = 0.f;
#pragma unroll
            for (int k = 0; k < NGS; ++k) { pr[k] = expf(il[k] - m); s += pr[k]; }
            const float inv = 1.0f / s;
#pragma unroll
            for (int k = 0; k < NGS; ++k) pr[k] *= inv;

            int i1 = 0;
            float v1 = pr[0];
#pragma unroll
            for (int k = 1; k < NGS; ++k)
                if (pr[k] > v1) { v1 = pr[k]; i1 = k; }
            int i2 = -1;
            float v2 = -3.0e38f;
#pragma unroll
            for (int k = 0; k < NGS; ++k)
                if (k != i1 && pr[k] > v2) { v2 = pr[k]; i2 = k; }

            if (d8 == 0) {
                const int id1 = experts[bg * NGS + i1];
                const int id2 = experts[bg * NGS + i2];
                outi[t] = make_float2((float)id1, (float)id2);
                outw[t] = make_float2(v1, v2);
            }
        }
    }
}

extern "C" void kernel_launch(void* const* d_in, const int* in_sizes, int n_in,
                              void* d_out, int out_size, void* d_ws, size_t ws_size,
                              hipStream_t stream) {
    const float* x  = (const float*)d_in[0];
    const float* gw = (const float*)d_in[1];
    const float* gb = (const float*)d_in[2];
    const float* iw = (const float*)d_in[3];
    const float* ib = (const float*)d_in[4];
    const int*   et = (const int*)d_in[5];
    float* out = (float*)d_out;

    router_k<<<dim3(NB / TOKS), dim3(TPB), 0, stream>>>(x, gw, gb, iw, ib, et, out);
}